// Round 6
// baseline (230.476 us; speedup 1.0000x reference)
//
#include <hip/hip_runtime.h>
#include <hip/hip_bf16.h>
#include <math.h>

// ---------------------------------------------------------------------------
// ClusteringModule: e = (z@W1+b1)@W2+b2 ; s = rownorm(1/(1+||e-c||)) ; c=argmax
// Round 9: single-variable experiment in the r8 skeleton — gemm inner loop
// swapped to mfma_f32_32x32x16_bf16 (wave tile 32x64 = 1x2 fragments of
// 32x32). Same LDS layout/staging/occupancy as r8's 121us gemm; -17% matrix
// pipe time, -50% MFMA issue slots at identical LDS traffic.
// split_z / split_w / head_kernel unchanged from r8.
// ---------------------------------------------------------------------------

typedef __bf16 bf16x8 __attribute__((ext_vector_type(8)));
typedef float  f32x4  __attribute__((ext_vector_type(4)));
typedef float  f32x16 __attribute__((ext_vector_type(16)));
typedef unsigned short ushort8 __attribute__((ext_vector_type(8)));

#define MROWS 2048
#define KDIM  12000
#define N1    1024
#define N2    64
#define NCL   100

constexpr int KT = 375;          // k-tiles of 32
constexpr int MT = 16;           // m-tiles of 128
constexpr int NT = 8;            // n-tiles of 128
constexpr int TILE_E = 4096;     // 128x32 bf16 elems per tile (8192 B)
constexpr long long AE = (long long)MT * KT * TILE_E;
constexpr long long BE = (long long)NT * KT * TILE_E;

__device__ __forceinline__ unsigned short f2bf(float f) {
  unsigned int u = __float_as_uint(f);
  return (unsigned short)((u + 0x7FFFu + ((u >> 16) & 1u)) >> 16);   // RNE
}
__device__ __forceinline__ float bf2f(unsigned short h) {
  return __uint_as_float(((unsigned int)h) << 16);
}

__device__ __forceinline__ void gl_lds16(const unsigned short* g, unsigned short* l) {
  __builtin_amdgcn_global_load_lds((const __attribute__((address_space(1))) void*)g,
                                   (__attribute__((address_space(3))) void*)l, 16, 0, 0);
}

// ------------------- pre-split: z -> Ah/Al (transpose-free) -----------------
__global__ __launch_bounds__(256) void split_z(const float* __restrict__ z,
                                               unsigned short* __restrict__ Ah,
                                               unsigned short* __restrict__ Al) {
  const int t  = threadIdx.x;
  const int kt = blockIdx.x, mt = blockIdx.y;
  const long long tb = (long long)(mt * KT + kt) * TILE_E;
#pragma unroll
  for (int i = 0; i < 2; ++i) {
    const int idx = i * 256 + t;           // 0..511
    const int r   = idx >> 2;              // 0..127
    const int k16 = idx & 3;               // 0..3
    const float* src = z + (long long)(mt * 128 + r) * KDIM + kt * 32 + k16 * 8;
    const float4 v0 = *(const float4*)src;
    const float4 v1 = *(const float4*)(src + 4);
    const float vv[8] = {v0.x, v0.y, v0.z, v0.w, v1.x, v1.y, v1.z, v1.w};
    ushort8 h, l;
#pragma unroll
    for (int j = 0; j < 8; ++j) {
      const unsigned short hs = f2bf(vv[j]);
      h[j] = hs; l[j] = f2bf(vv[j] - bf2f(hs));
    }
    const long long o = tb + (long long)(k16 * 128 + r) * 8;
    *(ushort8*)&Ah[o] = h;
    *(ushort8*)&Al[o] = l;
  }
}

// --------------------- pre-split: W1 -> Bh/Bl (transposed) ------------------
__global__ __launch_bounds__(256) void split_w(const float* __restrict__ W1,
                                               unsigned short* __restrict__ Bh,
                                               unsigned short* __restrict__ Bl) {
  __shared__ float tile[32][129];
  const int t = threadIdx.x;
  const int kt = blockIdx.x, nt = blockIdx.y;
  const float* src = W1 + (long long)(kt * 32) * N1 + nt * 128;
#pragma unroll
  for (int i = 0; i < 4; ++i) {
    const int idx = i * 256 + t, r = idx >> 5, c4 = idx & 31;
    const float4 v = *(const float4*)(src + (long long)r * N1 + c4 * 4);
    tile[r][c4 * 4 + 0] = v.x; tile[r][c4 * 4 + 1] = v.y;
    tile[r][c4 * 4 + 2] = v.z; tile[r][c4 * 4 + 3] = v.w;
  }
  __syncthreads();
  const long long tb = (long long)(nt * KT + kt) * TILE_E;
#pragma unroll
  for (int i = 0; i < 2; ++i) {
    const int q = i * 256 + t, k16 = q >> 7, col = q & 127;
    ushort8 h, l;
#pragma unroll
    for (int j = 0; j < 8; ++j) {
      const float f = tile[k16 * 8 + j][col];
      const unsigned short hs = f2bf(f);
      h[j] = hs; l[j] = f2bf(f - bf2f(hs));
    }
    *(ushort8*)&Bh[tb + q * 8] = h;
    *(ushort8*)&Bl[tb + q * 8] = l;
  }
}

// ----------------------- GEMM1: split-3 bf16 MFMA ---------------------------
// 128x128 tile, BK=32, 8 waves x (32x64) via 32x32x16 MFMA (1x2 frags/wave),
// K-split-4 -> 512 blocks of 512 thr. 2 blocks/CU (64KB dbuf) = 4 waves/SIMD.
__global__ __launch_bounds__(512, 4)
void gemm_split3(const unsigned short* __restrict__ Ah, const unsigned short* __restrict__ Al,
                 const unsigned short* __restrict__ Bh, const unsigned short* __restrict__ Bl,
                 const float* __restrict__ b1, float* __restrict__ e1p)
{
  __shared__ unsigned short lds[2][4][TILE_E];   // 64 KB
  const int t = threadIdx.x, lane = t & 63, w = t >> 6;   // w: 0..7
  const int wr = w >> 1, wc = w & 1;                      // wave tile: 32x64
  const int bid = blockIdx.x;
  const int wg = ((bid & 7) << 6) | (bid >> 3);  // XCD chunked swizzle, 512%8==0
  const int ks = wg >> 7;
  const int mt = (wg >> 3) & 15;
  const int nt = wg & 7;
  const int s0 = ks * 94;
  const int nst = (ks == 3) ? 93 : 94;

  const unsigned short* ga0 = Ah + (long long)(mt * KT + s0) * TILE_E;
  const unsigned short* ga1 = Al + (long long)(mt * KT + s0) * TILE_E;
  const unsigned short* ga2 = Bh + (long long)(nt * KT + s0) * TILE_E;
  const unsigned short* ga3 = Bl + (long long)(nt * KT + s0) * TILE_E;

  auto stage = [&](int buf, int s) {   // 512 thr x 16B = 8KB = one array each
    const long long so = (long long)s * TILE_E + t * 8;
    gl_lds16(ga0 + so, &lds[buf][0][t * 8]);
    gl_lds16(ga1 + so, &lds[buf][1][t * 8]);
    gl_lds16(ga2 + so, &lds[buf][2][t * 8]);
    gl_lds16(ga3 + so, &lds[buf][3][t * 8]);
  };

  f32x16 acc[2] = {};                 // acc[nf], nf: two 32x32 col-fragments
  const int row_l = lane & 31;        // row/col within 32x32 fragment
  const int kg    = lane >> 5;        // k-group: lane-half selects k16 pair

  stage(0, 0);
  __syncthreads();
  int buf = 0;
  for (int s = 0; s < nst; ++s) {
    if (s + 1 < nst) stage(buf ^ 1, s + 1);

    bf16x8 ah[2], al[2], bh[2][2], bl[2][2];   // [kh] / [kh][nf]
#pragma unroll
    for (int kh = 0; kh < 2; ++kh) {
      const int k16 = kh * 2 + kg;
      const int row = wr * 32 + row_l;
      ah[kh] = *(const bf16x8*)&lds[buf][0][k16 * 1024 + row * 8];
      al[kh] = *(const bf16x8*)&lds[buf][1][k16 * 1024 + row * 8];
#pragma unroll
      for (int nf = 0; nf < 2; ++nf) {
        const int col = wc * 64 + nf * 32 + row_l;
        bh[kh][nf] = *(const bf16x8*)&lds[buf][2][k16 * 1024 + col * 8];
        bl[kh][nf] = *(const bf16x8*)&lds[buf][3][k16 * 1024 + col * 8];
      }
    }
    __builtin_amdgcn_s_setprio(1);
#pragma unroll
    for (int kh = 0; kh < 2; ++kh)
#pragma unroll
      for (int nf = 0; nf < 2; ++nf)
        acc[nf] = __builtin_amdgcn_mfma_f32_32x32x16_bf16(ah[kh], bh[kh][nf], acc[nf], 0, 0, 0);
#pragma unroll
    for (int kh = 0; kh < 2; ++kh)
#pragma unroll
      for (int nf = 0; nf < 2; ++nf)
        acc[nf] = __builtin_amdgcn_mfma_f32_32x32x16_bf16(ah[kh], bl[kh][nf], acc[nf], 0, 0, 0);
#pragma unroll
    for (int kh = 0; kh < 2; ++kh)
#pragma unroll
      for (int nf = 0; nf < 2; ++nf)
        acc[nf] = __builtin_amdgcn_mfma_f32_32x32x16_bf16(al[kh], bh[kh][nf], acc[nf], 0, 0, 0);
    __builtin_amdgcn_s_setprio(0);
    __syncthreads();
    buf ^= 1;
  }

  // Epilogue: 32x32 C/D layout col=lane&31, row=(r&3)+8*(r>>2)+4*(lane>>5)
  // (verified end-to-end in r5: passed with identical absmax)
  float* eo = e1p + (long long)ks * MROWS * N1;
#pragma unroll
  for (int nf = 0; nf < 2; ++nf) {
    const int col = nt * 128 + wc * 64 + nf * 32 + row_l;
    const float bias = (ks == 0) ? b1[col] : 0.0f;
#pragma unroll
    for (int r = 0; r < 16; ++r) {
      const int row = mt * 128 + wr * 32 + (r & 3) + 8 * (r >> 2) + 4 * kg;
      eo[(long long)row * N1 + col] = acc[nf][r] + bias;
    }
  }
}

// ------------------------ GEMM2 + distances + argmax ------------------------
// r7 head: cooperative LDS reduction of NKS=4 partials (compile-time
// unrolled, coalesced f32x4), GEMM2 from LDS broadcast, distances + argmax.
constexpr int RPB = 8;
constexpr int NKS = 4;

__global__ __launch_bounds__(256, 2)
void head_kernel(const float* __restrict__ e1, const float* __restrict__ W2,
                 const float* __restrict__ b2, const float* __restrict__ cents,
                 float* __restrict__ eOut, float* __restrict__ sOut,
                 float* __restrict__ cOut)
{
  __shared__ float e_red[RPB][N1];        // 32 KB: reduced e1 rows
  __shared__ float cent_s[NCL * 65];      // 26 KB
  __shared__ float e_s[RPB][N2 + 4];
  const int t = threadIdx.x;
  const int r0 = blockIdx.x * RPB;
  constexpr long long PS = (long long)MROWS * N1;

  for (int i = t; i < NCL * N2; i += 256) {
    const int c = i >> 6, d = i & 63;
    cent_s[c * 65 + d] = cents[i];
  }

  // phase 1: reduce NKS partials into e_red (coalesced 1KB/wave loads)
#pragma unroll
  for (int v = 0; v < 8; ++v) {
    const int idx = v * 256 + t;          // 0..2047
    const int row = idx >> 8;             // 0..7
    const int c4  = idx & 255;            // f32x4 slot within row
    const float* src = e1 + (long long)(r0 + row) * N1 + c4 * 4;
    f32x4 x = *(const f32x4*)src;
#pragma unroll
    for (int p = 1; p < NKS; ++p) x += *(const f32x4*)(src + (long long)p * PS);
    *(f32x4*)&e_red[row][c4 * 4] = x;
  }
  __syncthreads();

  // phase 2: GEMM2 from LDS (wave-uniform broadcast reads, conflict-free)
  const int n = t & 63;
  const int rq = t >> 6;
  float acc0 = 0.f, acc1 = 0.f;
  for (int k = 0; k < N1; k += 4) {
    const f32x4 x0 = *(const f32x4*)&e_red[rq][k];
    const f32x4 x1 = *(const f32x4*)&e_red[rq + 4][k];
    const float w0 = W2[(k + 0) * N2 + n];
    const float w1 = W2[(k + 1) * N2 + n];
    const float w2 = W2[(k + 2) * N2 + n];
    const float w3 = W2[(k + 3) * N2 + n];
    acc0 = fmaf(x0[0], w0, acc0); acc0 = fmaf(x0[1], w1, acc0);
    acc0 = fmaf(x0[2], w2, acc0); acc0 = fmaf(x0[3], w3, acc0);
    acc1 = fmaf(x1[0], w0, acc1); acc1 = fmaf(x1[1], w1, acc1);
    acc1 = fmaf(x1[2], w2, acc1); acc1 = fmaf(x1[3], w3, acc1);
  }
  acc0 += b2[n]; acc1 += b2[n];
  eOut[(long long)(r0 + rq) * N2 + n]     = acc0;
  eOut[(long long)(r0 + rq + 4) * N2 + n] = acc1;
  e_s[rq][n]     = acc0;
  e_s[rq + 4][n] = acc1;
  __syncthreads();

  // phase 3: distances + row-normalize + argmax
  const int row = t >> 5;
  const int ci  = t & 31;
  float sum = 0.f, bestv = -1.f;
  int bestc = 0;
  float sv[4] = {0.f, 0.f, 0.f, 0.f};
#pragma unroll
  for (int j = 0; j < 4; ++j) {
    const int c = ci + 32 * j;
    if (c < NCL) {
      float d2 = 0.f;
#pragma unroll 8
      for (int d = 0; d < N2; ++d) {
        const float diff = e_s[row][d] - cent_s[c * 65 + d];
        d2 = fmaf(diff, diff, d2);
      }
      const float su = 1.0f / (1.0f + sqrtf(d2));
      sv[j] = su; sum += su;
      if (su > bestv) { bestv = su; bestc = c; }
    }
  }
#pragma unroll
  for (int off = 1; off < 32; off <<= 1) {
    sum += __shfl_xor(sum, off);
    const float ov = __shfl_xor(bestv, off);
    const int   oc = __shfl_xor(bestc, off);
    if (ov > bestv || (ov == bestv && oc < bestc)) { bestv = ov; bestc = oc; }
  }
  const float inv = 1.0f / sum;
#pragma unroll
  for (int j = 0; j < 4; ++j) {
    const int c = ci + 32 * j;
    if (c < NCL) sOut[(long long)(r0 + row) * NCL + c] = sv[j] * inv;
  }
  if (ci == 0) cOut[r0 + row] = (float)bestc;
}

// --------------------------------- launch -----------------------------------
extern "C" void kernel_launch(void* const* d_in, const int* in_sizes, int n_in,
                              void* d_out, int out_size, void* d_ws, size_t ws_size,
                              hipStream_t stream)
{
  const float* z     = (const float*)d_in[0];
  const float* W1    = (const float*)d_in[1];
  const float* b1    = (const float*)d_in[2];
  const float* W2    = (const float*)d_in[3];
  const float* b2    = (const float*)d_in[4];
  const float* cents = (const float*)d_in[5];
  float* out  = (float*)d_out;
  float* eOut = out;
  float* sOut = out + MROWS * N2;
  float* cOut = out + MROWS * N2 + MROWS * NCL;

  unsigned short* Ah = (unsigned short*)d_ws;
  unsigned short* Al = Ah + AE;
  unsigned short* Bh = Al + AE;
  unsigned short* Bl = Bh + BE;
  float* e1p = (float*)(Bl + BE);

  split_z<<<dim3(KT, MT), 256, 0, stream>>>(z, Ah, Al);
  split_w<<<dim3(KT, NT), 256, 0, stream>>>(W1, Bh, Bl);
  gemm_split3<<<512, 512, 0, stream>>>(Ah, Al, Bh, Bl, b1, e1p);
  head_kernel<<<MROWS / RPB, 256, 0, stream>>>(e1p, W2, b2, cents, eOut, sOut, cOut);
}

// Round 7
// 214.731 us; speedup vs baseline: 1.0733x; 1.0733x over previous
//
#include <hip/hip_runtime.h>
#include <hip/hip_bf16.h>
#include <math.h>

// ---------------------------------------------------------------------------
// ClusteringModule: e = (z@W1+b1)@W2+b2 ; s = rownorm(1/(1+||e-c||)) ; c=argmax
// Round 10: r8 skeleton (best: 209.8us; gemm=r3 16x16x32 split-3, head=r7).
// Single variable: gemm main-loop sync changed from __syncthreads() (vmcnt(0)
// drain) to raw s_barrier + counted s_waitcnt vmcnt(4), so the next-tile
// global_load_lds prefetch stays in flight across the barrier (T4).
// Barrier pattern correctness-validated in r4; occupancy kept at 2 blk/CU.
// ---------------------------------------------------------------------------

typedef __bf16 bf16x8 __attribute__((ext_vector_type(8)));
typedef float  f32x4  __attribute__((ext_vector_type(4)));
typedef unsigned short ushort8 __attribute__((ext_vector_type(8)));

#define MROWS 2048
#define KDIM  12000
#define N1    1024
#define N2    64
#define NCL   100

constexpr int KT = 375;          // k-tiles of 32
constexpr int MT = 16;           // m-tiles of 128
constexpr int NT = 8;            // n-tiles of 128
constexpr int TILE_E = 4096;     // 128x32 bf16 elems per tile (8192 B)
constexpr long long AE = (long long)MT * KT * TILE_E;
constexpr long long BE = (long long)NT * KT * TILE_E;

__device__ __forceinline__ unsigned short f2bf(float f) {
  unsigned int u = __float_as_uint(f);
  return (unsigned short)((u + 0x7FFFu + ((u >> 16) & 1u)) >> 16);   // RNE
}
__device__ __forceinline__ float bf2f(unsigned short h) {
  return __uint_as_float(((unsigned int)h) << 16);
}

__device__ __forceinline__ void gl_lds16(const unsigned short* g, unsigned short* l) {
  __builtin_amdgcn_global_load_lds((const __attribute__((address_space(1))) void*)g,
                                   (__attribute__((address_space(3))) void*)l, 16, 0, 0);
}

// ------------------- pre-split: z -> Ah/Al (transpose-free) -----------------
__global__ __launch_bounds__(256) void split_z(const float* __restrict__ z,
                                               unsigned short* __restrict__ Ah,
                                               unsigned short* __restrict__ Al) {
  const int t  = threadIdx.x;
  const int kt = blockIdx.x, mt = blockIdx.y;
  const long long tb = (long long)(mt * KT + kt) * TILE_E;
#pragma unroll
  for (int i = 0; i < 2; ++i) {
    const int idx = i * 256 + t;           // 0..511
    const int r   = idx >> 2;              // 0..127
    const int k16 = idx & 3;               // 0..3
    const float* src = z + (long long)(mt * 128 + r) * KDIM + kt * 32 + k16 * 8;
    const float4 v0 = *(const float4*)src;
    const float4 v1 = *(const float4*)(src + 4);
    const float vv[8] = {v0.x, v0.y, v0.z, v0.w, v1.x, v1.y, v1.z, v1.w};
    ushort8 h, l;
#pragma unroll
    for (int j = 0; j < 8; ++j) {
      const unsigned short hs = f2bf(vv[j]);
      h[j] = hs; l[j] = f2bf(vv[j] - bf2f(hs));
    }
    const long long o = tb + (long long)(k16 * 128 + r) * 8;
    *(ushort8*)&Ah[o] = h;
    *(ushort8*)&Al[o] = l;
  }
}

// --------------------- pre-split: W1 -> Bh/Bl (transposed) ------------------
__global__ __launch_bounds__(256) void split_w(const float* __restrict__ W1,
                                               unsigned short* __restrict__ Bh,
                                               unsigned short* __restrict__ Bl) {
  __shared__ float tile[32][129];
  const int t = threadIdx.x;
  const int kt = blockIdx.x, nt = blockIdx.y;
  const float* src = W1 + (long long)(kt * 32) * N1 + nt * 128;
#pragma unroll
  for (int i = 0; i < 4; ++i) {
    const int idx = i * 256 + t, r = idx >> 5, c4 = idx & 31;
    const float4 v = *(const float4*)(src + (long long)r * N1 + c4 * 4);
    tile[r][c4 * 4 + 0] = v.x; tile[r][c4 * 4 + 1] = v.y;
    tile[r][c4 * 4 + 2] = v.z; tile[r][c4 * 4 + 3] = v.w;
  }
  __syncthreads();
  const long long tb = (long long)(nt * KT + kt) * TILE_E;
#pragma unroll
  for (int i = 0; i < 2; ++i) {
    const int q = i * 256 + t, k16 = q >> 7, col = q & 127;
    ushort8 h, l;
#pragma unroll
    for (int j = 0; j < 8; ++j) {
      const float f = tile[k16 * 8 + j][col];
      const unsigned short hs = f2bf(f);
      h[j] = hs; l[j] = f2bf(f - bf2f(hs));
    }
    *(ushort8*)&Bh[tb + q * 8] = h;
    *(ushort8*)&Bl[tb + q * 8] = l;
  }
}

// ----------------------- GEMM1: split-3 bf16 MFMA ---------------------------
// 128x128 tile, BK=32, 8 waves x (32x64), K-split-4 -> 512 blocks of 512 thr.
// 2 blocks/CU (64KB LDS dbuf) = 16 waves/CU = 4 waves/SIMD.
// Counted-vmcnt pipeline: 4 gl_lds per stage; vmcnt(4) waits only the
// previous stage, keeping the new prefetch in flight across both barriers.
__global__ __launch_bounds__(512, 4)
void gemm_split3(const unsigned short* __restrict__ Ah, const unsigned short* __restrict__ Al,
                 const unsigned short* __restrict__ Bh, const unsigned short* __restrict__ Bl,
                 const float* __restrict__ b1, float* __restrict__ e1p)
{
  __shared__ unsigned short lds[2][4][TILE_E];   // 64 KB
  const int t = threadIdx.x, lane = t & 63, w = t >> 6;   // w: 0..7
  const int wr = w >> 1, wc = w & 1;                      // wave tile: 32x64
  const int bid = blockIdx.x;
  const int wg = ((bid & 7) << 6) | (bid >> 3);  // XCD chunked swizzle, 512%8==0
  const int ks = wg >> 7;
  const int mt = (wg >> 3) & 15;
  const int nt = wg & 7;
  const int s0 = ks * 94;
  const int nst = (ks == 3) ? 93 : 94;

  const unsigned short* ga0 = Ah + (long long)(mt * KT + s0) * TILE_E;
  const unsigned short* ga1 = Al + (long long)(mt * KT + s0) * TILE_E;
  const unsigned short* ga2 = Bh + (long long)(nt * KT + s0) * TILE_E;
  const unsigned short* ga3 = Bl + (long long)(nt * KT + s0) * TILE_E;

  auto stage = [&](int buf, int s) {   // 512 thr x 16B = 8KB = one array each
    const long long so = (long long)s * TILE_E + t * 8;
    gl_lds16(ga0 + so, &lds[buf][0][t * 8]);
    gl_lds16(ga1 + so, &lds[buf][1][t * 8]);
    gl_lds16(ga2 + so, &lds[buf][2][t * 8]);
    gl_lds16(ga3 + so, &lds[buf][3][t * 8]);
  };

  f32x4 acc[2][4] = {};
  stage(0, 0);
  int buf = 0;
  for (int s = 0; s < nst; ++s) {
    if (s + 1 < nst) {
      stage(buf ^ 1, s + 1);                           // 4 loads for next tile
      asm volatile("s_waitcnt vmcnt(4)" ::: "memory"); // this tile's 4 done
    } else {
      asm volatile("s_waitcnt vmcnt(0)" ::: "memory"); // final tile done
    }
    __builtin_amdgcn_s_barrier();                      // all waves: tile ready
    __builtin_amdgcn_sched_barrier(0);

    const int fr = lane & 15, k16 = lane >> 4;
    bf16x8 ah[2], al[2], bh[4], bl[4];
#pragma unroll
    for (int mf = 0; mf < 2; ++mf) {
      const int row = wr * 32 + mf * 16 + fr;
      ah[mf] = *(const bf16x8*)&lds[buf][0][k16 * 1024 + row * 8];
      al[mf] = *(const bf16x8*)&lds[buf][1][k16 * 1024 + row * 8];
    }
#pragma unroll
    for (int nf = 0; nf < 4; ++nf) {
      const int col = wc * 64 + nf * 16 + fr;
      bh[nf] = *(const bf16x8*)&lds[buf][2][k16 * 1024 + col * 8];
      bl[nf] = *(const bf16x8*)&lds[buf][3][k16 * 1024 + col * 8];
    }
    __builtin_amdgcn_s_setprio(1);
#pragma unroll
    for (int mf = 0; mf < 2; ++mf)
#pragma unroll
      for (int nf = 0; nf < 4; ++nf)
        acc[mf][nf] = __builtin_amdgcn_mfma_f32_16x16x32_bf16(ah[mf], bh[nf], acc[mf][nf], 0, 0, 0);
#pragma unroll
    for (int mf = 0; mf < 2; ++mf)
#pragma unroll
      for (int nf = 0; nf < 4; ++nf)
        acc[mf][nf] = __builtin_amdgcn_mfma_f32_16x16x32_bf16(ah[mf], bl[nf], acc[mf][nf], 0, 0, 0);
#pragma unroll
    for (int mf = 0; mf < 2; ++mf)
#pragma unroll
      for (int nf = 0; nf < 4; ++nf)
        acc[mf][nf] = __builtin_amdgcn_mfma_f32_16x16x32_bf16(al[mf], bh[nf], acc[mf][nf], 0, 0, 0);
    __builtin_amdgcn_s_setprio(0);
    __builtin_amdgcn_s_barrier();                      // reads done before overwrite
    __builtin_amdgcn_sched_barrier(0);
    buf ^= 1;
  }

  float* eo = e1p + (long long)ks * MROWS * N1;
#pragma unroll
  for (int mf = 0; mf < 2; ++mf) {
    const int r0 = mt * 128 + wr * 32 + mf * 16 + ((lane >> 4) << 2);
#pragma unroll
    for (int nf = 0; nf < 4; ++nf) {
      const int col = nt * 128 + wc * 64 + nf * 16 + (lane & 15);
      const float bias = (ks == 0) ? b1[col] : 0.0f;
#pragma unroll
      for (int r = 0; r < 4; ++r)
        eo[(long long)(r0 + r) * N1 + col] = acc[mf][nf][r] + bias;
    }
  }
}

// ------------------------ GEMM2 + distances + argmax ------------------------
// r7 head: cooperative LDS reduction of NKS=4 partials (compile-time
// unrolled, coalesced f32x4), GEMM2 from LDS broadcast, distances + argmax.
constexpr int RPB = 8;
constexpr int NKS = 4;

__global__ __launch_bounds__(256, 2)
void head_kernel(const float* __restrict__ e1, const float* __restrict__ W2,
                 const float* __restrict__ b2, const float* __restrict__ cents,
                 float* __restrict__ eOut, float* __restrict__ sOut,
                 float* __restrict__ cOut)
{
  __shared__ float e_red[RPB][N1];        // 32 KB: reduced e1 rows
  __shared__ float cent_s[NCL * 65];      // 26 KB
  __shared__ float e_s[RPB][N2 + 4];
  const int t = threadIdx.x;
  const int r0 = blockIdx.x * RPB;
  constexpr long long PS = (long long)MROWS * N1;

  for (int i = t; i < NCL * N2; i += 256) {
    const int c = i >> 6, d = i & 63;
    cent_s[c * 65 + d] = cents[i];
  }

  // phase 1: reduce NKS partials into e_red (coalesced 1KB/wave loads)
#pragma unroll
  for (int v = 0; v < 8; ++v) {
    const int idx = v * 256 + t;          // 0..2047
    const int row = idx >> 8;             // 0..7
    const int c4  = idx & 255;            // f32x4 slot within row
    const float* src = e1 + (long long)(r0 + row) * N1 + c4 * 4;
    f32x4 x = *(const f32x4*)src;
#pragma unroll
    for (int p = 1; p < NKS; ++p) x += *(const f32x4*)(src + (long long)p * PS);
    *(f32x4*)&e_red[row][c4 * 4] = x;
  }
  __syncthreads();

  // phase 2: GEMM2 from LDS (wave-uniform broadcast reads, conflict-free)
  const int n = t & 63;
  const int rq = t >> 6;
  float acc0 = 0.f, acc1 = 0.f;
  for (int k = 0; k < N1; k += 4) {
    const f32x4 x0 = *(const f32x4*)&e_red[rq][k];
    const f32x4 x1 = *(const f32x4*)&e_red[rq + 4][k];
    const float w0 = W2[(k + 0) * N2 + n];
    const float w1 = W2[(k + 1) * N2 + n];
    const float w2 = W2[(k + 2) * N2 + n];
    const float w3 = W2[(k + 3) * N2 + n];
    acc0 = fmaf(x0[0], w0, acc0); acc0 = fmaf(x0[1], w1, acc0);
    acc0 = fmaf(x0[2], w2, acc0); acc0 = fmaf(x0[3], w3, acc0);
    acc1 = fmaf(x1[0], w0, acc1); acc1 = fmaf(x1[1], w1, acc1);
    acc1 = fmaf(x1[2], w2, acc1); acc1 = fmaf(x1[3], w3, acc1);
  }
  acc0 += b2[n]; acc1 += b2[n];
  eOut[(long long)(r0 + rq) * N2 + n]     = acc0;
  eOut[(long long)(r0 + rq + 4) * N2 + n] = acc1;
  e_s[rq][n]     = acc0;
  e_s[rq + 4][n] = acc1;
  __syncthreads();

  // phase 3: distances + row-normalize + argmax
  const int row = t >> 5;
  const int ci  = t & 31;
  float sum = 0.f, bestv = -1.f;
  int bestc = 0;
  float sv[4] = {0.f, 0.f, 0.f, 0.f};
#pragma unroll
  for (int j = 0; j < 4; ++j) {
    const int c = ci + 32 * j;
    if (c < NCL) {
      float d2 = 0.f;
#pragma unroll 8
      for (int d = 0; d < N2; ++d) {
        const float diff = e_s[row][d] - cent_s[c * 65 + d];
        d2 = fmaf(diff, diff, d2);
      }
      const float su = 1.0f / (1.0f + sqrtf(d2));
      sv[j] = su; sum += su;
      if (su > bestv) { bestv = su; bestc = c; }
    }
  }
#pragma unroll
  for (int off = 1; off < 32; off <<= 1) {
    sum += __shfl_xor(sum, off);
    const float ov = __shfl_xor(bestv, off);
    const int   oc = __shfl_xor(bestc, off);
    if (ov > bestv || (ov == bestv && oc < bestc)) { bestv = ov; bestc = oc; }
  }
  const float inv = 1.0f / sum;
#pragma unroll
  for (int j = 0; j < 4; ++j) {
    const int c = ci + 32 * j;
    if (c < NCL) sOut[(long long)(r0 + row) * NCL + c] = sv[j] * inv;
  }
  if (ci == 0) cOut[r0 + row] = (float)bestc;
}

// --------------------------------- launch -----------------------------------
extern "C" void kernel_launch(void* const* d_in, const int* in_sizes, int n_in,
                              void* d_out, int out_size, void* d_ws, size_t ws_size,
                              hipStream_t stream)
{
  const float* z     = (const float*)d_in[0];
  const float* W1    = (const float*)d_in[1];
  const float* b1    = (const float*)d_in[2];
  const float* W2    = (const float*)d_in[3];
  const float* b2    = (const float*)d_in[4];
  const float* cents = (const float*)d_in[5];
  float* out  = (float*)d_out;
  float* eOut = out;
  float* sOut = out + MROWS * N2;
  float* cOut = out + MROWS * N2 + MROWS * NCL;

  unsigned short* Ah = (unsigned short*)d_ws;
  unsigned short* Al = Ah + AE;
  unsigned short* Bh = Al + AE;
  unsigned short* Bl = Bh + BE;
  float* e1p = (float*)(Bl + BE);

  split_z<<<dim3(KT, MT), 256, 0, stream>>>(z, Ah, Al);
  split_w<<<dim3(KT, NT), 256, 0, stream>>>(W1, Bh, Bl);
  gemm_split3<<<512, 512, 0, stream>>>(Ah, Al, Bh, Bl, b1, e1p);
  head_kernel<<<MROWS / RPB, 256, 0, stream>>>(e1p, W2, b2, cents, eOut, sOut, cOut);
}

// Round 9
// 203.760 us; speedup vs baseline: 1.1311x; 1.0538x over previous
//
#include <hip/hip_runtime.h>
#include <hip/hip_bf16.h>
#include <math.h>

// ---------------------------------------------------------------------------
// ClusteringModule: e = (z@W1+b1)@W2+b2 ; s = rownorm(1/(1+||e-c||)) ; c=argmax
// Round 12: consolidation. gemm_split3 + head_kernel byte-identical to r8
// (best verified: 209.8us total, gemm 121us). Single change: split_z and
// split_w fused into one kernel/launch (grid (KT, MT+NT), branch on y) so
// the two HBM-bound streams overlap and one launch gap disappears.
// Precision scheme unchanged: bf16 split-3 (r11 proved 3 passes is the
// floor for exact argmax).
// ---------------------------------------------------------------------------

typedef __bf16 bf16x8 __attribute__((ext_vector_type(8)));
typedef float  f32x4  __attribute__((ext_vector_type(4)));
typedef unsigned short ushort8 __attribute__((ext_vector_type(8)));

#define MROWS 2048
#define KDIM  12000
#define N1    1024
#define N2    64
#define NCL   100

constexpr int KT = 375;          // k-tiles of 32
constexpr int MT = 16;           // m-tiles of 128
constexpr int NT = 8;           // n-tiles of 128
constexpr int TILE_E = 4096;     // 128x32 bf16 elems per tile (8192 B)
constexpr long long AE = (long long)MT * KT * TILE_E;
constexpr long long BE = (long long)NT * KT * TILE_E;

__device__ __forceinline__ unsigned short f2bf(float f) {
  unsigned int u = __float_as_uint(f);
  return (unsigned short)((u + 0x7FFFu + ((u >> 16) & 1u)) >> 16);   // RNE
}
__device__ __forceinline__ float bf2f(unsigned short h) {
  return __uint_as_float(((unsigned int)h) << 16);
}

__device__ __forceinline__ void gl_lds16(const unsigned short* g, unsigned short* l) {
  __builtin_amdgcn_global_load_lds((const __attribute__((address_space(1))) void*)g,
                                   (__attribute__((address_space(3))) void*)l, 16, 0, 0);
}

// ------------- fused pre-split: z -> Ah/Al  and  W1 -> Bh/Bl ---------------
// blockIdx.y < MT  : z-path (transpose-free streaming split, r3-verified)
// blockIdx.y >= MT : W1-path (LDS-transposed split, r0-verified)
__global__ __launch_bounds__(256)
void split_zw(const float* __restrict__ z, const float* __restrict__ W1,
              unsigned short* __restrict__ Ah, unsigned short* __restrict__ Al,
              unsigned short* __restrict__ Bh, unsigned short* __restrict__ Bl)
{
  __shared__ float tile[32][129];          // used by W1-path only (16.5 KB)
  const int t  = threadIdx.x;
  const int kt = blockIdx.x;

  if (blockIdx.y < MT) {
    // ---------------- z path ----------------
    const int mt = blockIdx.y;
    const long long tb = (long long)(mt * KT + kt) * TILE_E;
#pragma unroll
    for (int i = 0; i < 2; ++i) {
      const int idx = i * 256 + t;           // 0..511
      const int r   = idx >> 2;              // 0..127
      const int k16 = idx & 3;               // 0..3
      const float* src = z + (long long)(mt * 128 + r) * KDIM + kt * 32 + k16 * 8;
      const float4 v0 = *(const float4*)src;
      const float4 v1 = *(const float4*)(src + 4);
      const float vv[8] = {v0.x, v0.y, v0.z, v0.w, v1.x, v1.y, v1.z, v1.w};
      ushort8 h, l;
#pragma unroll
      for (int j = 0; j < 8; ++j) {
        const unsigned short hs = f2bf(vv[j]);
        h[j] = hs; l[j] = f2bf(vv[j] - bf2f(hs));
      }
      const long long o = tb + (long long)(k16 * 128 + r) * 8;
      *(ushort8*)&Ah[o] = h;
      *(ushort8*)&Al[o] = l;
    }
  } else {
    // ---------------- W1 path ----------------
    const int nt = blockIdx.y - MT;
    const float* src = W1 + (long long)(kt * 32) * N1 + nt * 128;
#pragma unroll
    for (int i = 0; i < 4; ++i) {
      const int idx = i * 256 + t, r = idx >> 5, c4 = idx & 31;
      const float4 v = *(const float4*)(src + (long long)r * N1 + c4 * 4);
      tile[r][c4 * 4 + 0] = v.x; tile[r][c4 * 4 + 1] = v.y;
      tile[r][c4 * 4 + 2] = v.z; tile[r][c4 * 4 + 3] = v.w;
    }
    __syncthreads();
    const long long tb = (long long)(nt * KT + kt) * TILE_E;
#pragma unroll
    for (int i = 0; i < 2; ++i) {
      const int q = i * 256 + t, k16 = q >> 7, col = q & 127;
      ushort8 h, l;
#pragma unroll
      for (int j = 0; j < 8; ++j) {
        const float f = tile[k16 * 8 + j][col];
        const unsigned short hs = f2bf(f);
        h[j] = hs; l[j] = f2bf(f - bf2f(hs));
      }
      *(ushort8*)&Bh[tb + q * 8] = h;
      *(ushort8*)&Bl[tb + q * 8] = l;
    }
  }
}

// ----------------------- GEMM1: split-3 bf16 MFMA ---------------------------
// 128x128 tile, BK=32, 8 waves x (32x64), K-split-4 -> 512 blocks of 512 thr.
// 2 blocks/CU (64KB LDS dbuf) = 16 waves/CU = 4 waves/SIMD.  [r3/r8: 121us]
__global__ __launch_bounds__(512, 4)
void gemm_split3(const unsigned short* __restrict__ Ah, const unsigned short* __restrict__ Al,
                 const unsigned short* __restrict__ Bh, const unsigned short* __restrict__ Bl,
                 const float* __restrict__ b1, float* __restrict__ e1p)
{
  __shared__ unsigned short lds[2][4][TILE_E];   // 64 KB
  const int t = threadIdx.x, lane = t & 63, w = t >> 6;   // w: 0..7
  const int wr = w >> 1, wc = w & 1;                      // wave tile: 32x64
  const int bid = blockIdx.x;
  const int wg = ((bid & 7) << 6) | (bid >> 3);  // XCD chunked swizzle, 512%8==0
  const int ks = wg >> 7;
  const int mt = (wg >> 3) & 15;
  const int nt = wg & 7;
  const int s0 = ks * 94;
  const int nst = (ks == 3) ? 93 : 94;

  const unsigned short* ga0 = Ah + (long long)(mt * KT + s0) * TILE_E;
  const unsigned short* ga1 = Al + (long long)(mt * KT + s0) * TILE_E;
  const unsigned short* ga2 = Bh + (long long)(nt * KT + s0) * TILE_E;
  const unsigned short* ga3 = Bl + (long long)(nt * KT + s0) * TILE_E;

  auto stage = [&](int buf, int s) {   // 512 thr x 16B = 8KB = one array each
    const long long so = (long long)s * TILE_E + t * 8;
    gl_lds16(ga0 + so, &lds[buf][0][t * 8]);
    gl_lds16(ga1 + so, &lds[buf][1][t * 8]);
    gl_lds16(ga2 + so, &lds[buf][2][t * 8]);
    gl_lds16(ga3 + so, &lds[buf][3][t * 8]);
  };

  f32x4 acc[2][4] = {};
  stage(0, 0);
  __syncthreads();
  int buf = 0;
  for (int s = 0; s < nst; ++s) {
    if (s + 1 < nst) stage(buf ^ 1, s + 1);

    const int fr = lane & 15, k16 = lane >> 4;
    bf16x8 ah[2], al[2], bh[4], bl[4];
#pragma unroll
    for (int mf = 0; mf < 2; ++mf) {
      const int row = wr * 32 + mf * 16 + fr;
      ah[mf] = *(const bf16x8*)&lds[buf][0][k16 * 1024 + row * 8];
      al[mf] = *(const bf16x8*)&lds[buf][1][k16 * 1024 + row * 8];
    }
#pragma unroll
    for (int nf = 0; nf < 4; ++nf) {
      const int col = wc * 64 + nf * 16 + fr;
      bh[nf] = *(const bf16x8*)&lds[buf][2][k16 * 1024 + col * 8];
      bl[nf] = *(const bf16x8*)&lds[buf][3][k16 * 1024 + col * 8];
    }
    __builtin_amdgcn_s_setprio(1);
#pragma unroll
    for (int mf = 0; mf < 2; ++mf)
#pragma unroll
      for (int nf = 0; nf < 4; ++nf)
        acc[mf][nf] = __builtin_amdgcn_mfma_f32_16x16x32_bf16(ah[mf], bh[nf], acc[mf][nf], 0, 0, 0);
#pragma unroll
    for (int mf = 0; mf < 2; ++mf)
#pragma unroll
      for (int nf = 0; nf < 4; ++nf)
        acc[mf][nf] = __builtin_amdgcn_mfma_f32_16x16x32_bf16(ah[mf], bl[nf], acc[mf][nf], 0, 0, 0);
#pragma unroll
    for (int mf = 0; mf < 2; ++mf)
#pragma unroll
      for (int nf = 0; nf < 4; ++nf)
        acc[mf][nf] = __builtin_amdgcn_mfma_f32_16x16x32_bf16(al[mf], bh[nf], acc[mf][nf], 0, 0, 0);
    __builtin_amdgcn_s_setprio(0);
    __syncthreads();
    buf ^= 1;
  }

  float* eo = e1p + (long long)ks * MROWS * N1;
#pragma unroll
  for (int mf = 0; mf < 2; ++mf) {
    const int r0 = mt * 128 + wr * 32 + mf * 16 + ((lane >> 4) << 2);
#pragma unroll
    for (int nf = 0; nf < 4; ++nf) {
      const int col = nt * 128 + wc * 64 + nf * 16 + (lane & 15);
      const float bias = (ks == 0) ? b1[col] : 0.0f;
#pragma unroll
      for (int r = 0; r < 4; ++r)
        eo[(long long)(r0 + r) * N1 + col] = acc[mf][nf][r] + bias;
    }
  }
}

// ------------------------ GEMM2 + distances + argmax ------------------------
// r7 head: cooperative LDS reduction of NKS=4 partials (compile-time
// unrolled, coalesced f32x4), GEMM2 from LDS broadcast, distances + argmax.
constexpr int RPB = 8;
constexpr int NKS = 4;

__global__ __launch_bounds__(256, 2)
void head_kernel(const float* __restrict__ e1, const float* __restrict__ W2,
                 const float* __restrict__ b2, const float* __restrict__ cents,
                 float* __restrict__ eOut, float* __restrict__ sOut,
                 float* __restrict__ cOut)
{
  __shared__ float e_red[RPB][N1];        // 32 KB: reduced e1 rows
  __shared__ float cent_s[NCL * 65];      // 26 KB
  __shared__ float e_s[RPB][N2 + 4];
  const int t = threadIdx.x;
  const int r0 = blockIdx.x * RPB;
  constexpr long long PS = (long long)MROWS * N1;

  for (int i = t; i < NCL * N2; i += 256) {
    const int c = i >> 6, d = i & 63;
    cent_s[c * 65 + d] = cents[i];
  }

  // phase 1: reduce NKS partials into e_red (coalesced 1KB/wave loads)
#pragma unroll
  for (int v = 0; v < 8; ++v) {
    const int idx = v * 256 + t;          // 0..2047
    const int row = idx >> 8;             // 0..7
    const int c4  = idx & 255;            // f32x4 slot within row
    const float* src = e1 + (long long)(r0 + row) * N1 + c4 * 4;
    f32x4 x = *(const f32x4*)src;
#pragma unroll
    for (int p = 1; p < NKS; ++p) x += *(const f32x4*)(src + (long long)p * PS);
    *(f32x4*)&e_red[row][c4 * 4] = x;
  }
  __syncthreads();

  // phase 2: GEMM2 from LDS (wave-uniform broadcast reads, conflict-free)
  const int n = t & 63;
  const int rq = t >> 6;
  float acc0 = 0.f, acc1 = 0.f;
  for (int k = 0; k < N1; k += 4) {
    const f32x4 x0 = *(const f32x4*)&e_red[rq][k];
    const f32x4 x1 = *(const f32x4*)&e_red[rq + 4][k];
    const float w0 = W2[(k + 0) * N2 + n];
    const float w1 = W2[(k + 1) * N2 + n];
    const float w2 = W2[(k + 2) * N2 + n];
    const float w3 = W2[(k + 3) * N2 + n];
    acc0 = fmaf(x0[0], w0, acc0); acc0 = fmaf(x0[1], w1, acc0);
    acc0 = fmaf(x0[2], w2, acc0); acc0 = fmaf(x0[3], w3, acc0);
    acc1 = fmaf(x1[0], w0, acc1); acc1 = fmaf(x1[1], w1, acc1);
    acc1 = fmaf(x1[2], w2, acc1); acc1 = fmaf(x1[3], w3, acc1);
  }
  acc0 += b2[n]; acc1 += b2[n];
  eOut[(long long)(r0 + rq) * N2 + n]     = acc0;
  eOut[(long long)(r0 + rq + 4) * N2 + n] = acc1;
  e_s[rq][n]     = acc0;
  e_s[rq + 4][n] = acc1;
  __syncthreads();

  // phase 3: distances + row-normalize + argmax
  const int row = t >> 5;
  const int ci  = t & 31;
  float sum = 0.f, bestv = -1.f;
  int bestc = 0;
  float sv[4] = {0.f, 0.f, 0.f, 0.f};
#pragma unroll
  for (int j = 0; j < 4; ++j) {
    const int c = ci + 32 * j;
    if (c < NCL) {
      float d2 = 0.f;
#pragma unroll 8
      for (int d = 0; d < N2; ++d) {
        const float diff = e_s[row][d] - cent_s[c * 65 + d];
        d2 = fmaf(diff, diff, d2);
      }
      const float su = 1.0f / (1.0f + sqrtf(d2));
      sv[j] = su; sum += su;
      if (su > bestv) { bestv = su; bestc = c; }
    }
  }
#pragma unroll
  for (int off = 1; off < 32; off <<= 1) {
    sum += __shfl_xor(sum, off);
    const float ov = __shfl_xor(bestv, off);
    const int   oc = __shfl_xor(bestc, off);
    if (ov > bestv || (ov == bestv && oc < bestc)) { bestv = ov; bestc = oc; }
  }
  const float inv = 1.0f / sum;
#pragma unroll
  for (int j = 0; j < 4; ++j) {
    const int c = ci + 32 * j;
    if (c < NCL) sOut[(long long)(r0 + row) * NCL + c] = sv[j] * inv;
  }
  if (ci == 0) cOut[r0 + row] = (float)bestc;
}

// --------------------------------- launch -----------------------------------
extern "C" void kernel_launch(void* const* d_in, const int* in_sizes, int n_in,
                              void* d_out, int out_size, void* d_ws, size_t ws_size,
                              hipStream_t stream)
{
  const float* z     = (const float*)d_in[0];
  const float* W1    = (const float*)d_in[1];
  const float* b1    = (const float*)d_in[2];
  const float* W2    = (const float*)d_in[3];
  const float* b2    = (const float*)d_in[4];
  const float* cents = (const float*)d_in[5];
  float* out  = (float*)d_out;
  float* eOut = out;
  float* sOut = out + MROWS * N2;
  float* cOut = out + MROWS * N2 + MROWS * NCL;

  unsigned short* Ah = (unsigned short*)d_ws;
  unsigned short* Al = Ah + AE;
  unsigned short* Bh = Al + AE;
  unsigned short* Bl = Bh + BE;
  float* e1p = (float*)(Bl + BE);

  split_zw<<<dim3(KT, MT + NT), 256, 0, stream>>>(z, W1, Ah, Al, Bh, Bl);
  gemm_split3<<<512, 512, 0, stream>>>(Ah, Al, Bh, Bl, b1, e1p);
  head_kernel<<<MROWS / RPB, 256, 0, stream>>>(e1p, W2, b2, cents, eOut, sOut, cOut);
}

// Round 10
// 201.987 us; speedup vs baseline: 1.1410x; 1.0088x over previous
//
#include <hip/hip_runtime.h>
#include <hip/hip_bf16.h>
#include <math.h>

// ---------------------------------------------------------------------------
// ClusteringModule: e = (z@W1+b1)@W2+b2 ; s = rownorm(1/(1+||e-c||)) ; c=argmax
// Round 13: LDS-traffic attack. GEMM1 = 128x256 block tile, 8 waves of 64x64
// (16x16x32 MFMA, 4x4 frags, 3 passes), SINGLE-buffered 48KB LDS, 2 blk/CU
// (4 waves/SIMD kept). Halves LDS bytes/FLOP (96->64KB frag reads per
// block-step at 2x work, no operand re-reads) so MFMA becomes the binding
// pipe; the single-buffer stage stall is covered by the co-resident block.
// K-split-8 (grid 512). head NKS=8. split_zw unchanged from r12.
// ---------------------------------------------------------------------------

typedef __bf16 bf16x8 __attribute__((ext_vector_type(8)));
typedef float  f32x4  __attribute__((ext_vector_type(4)));
typedef unsigned short ushort8 __attribute__((ext_vector_type(8)));

#define MROWS 2048
#define KDIM  12000
#define N1    1024
#define N2    64
#define NCL   100

constexpr int KT = 375;          // k-tiles of 32
constexpr int MT = 16;           // m-tiles of 128
constexpr int NT = 8;            // n-tiles of 128 (split layout unchanged)
constexpr int TILE_E = 4096;     // 128x32 bf16 elems per tile (8192 B)
constexpr long long AE = (long long)MT * KT * TILE_E;
constexpr long long BE = (long long)NT * KT * TILE_E;
constexpr int NKS = 8;           // K-split slices
constexpr int QS  = 47;          // k-steps per slice (last: 46)

__device__ __forceinline__ unsigned short f2bf(float f) {
  unsigned int u = __float_as_uint(f);
  return (unsigned short)((u + 0x7FFFu + ((u >> 16) & 1u)) >> 16);   // RNE
}
__device__ __forceinline__ float bf2f(unsigned short h) {
  return __uint_as_float(((unsigned int)h) << 16);
}

__device__ __forceinline__ void gl_lds16(const unsigned short* g, unsigned short* l) {
  __builtin_amdgcn_global_load_lds((const __attribute__((address_space(1))) void*)g,
                                   (__attribute__((address_space(3))) void*)l, 16, 0, 0);
}

// ------------- fused pre-split: z -> Ah/Al  and  W1 -> Bh/Bl ---------------
__global__ __launch_bounds__(256)
void split_zw(const float* __restrict__ z, const float* __restrict__ W1,
              unsigned short* __restrict__ Ah, unsigned short* __restrict__ Al,
              unsigned short* __restrict__ Bh, unsigned short* __restrict__ Bl)
{
  __shared__ float tile[32][129];          // W1-path only (16.5 KB)
  const int t  = threadIdx.x;
  const int kt = blockIdx.x;

  if (blockIdx.y < MT) {
    // ---------------- z path ----------------
    const int mt = blockIdx.y;
    const long long tb = (long long)(mt * KT + kt) * TILE_E;
#pragma unroll
    for (int i = 0; i < 2; ++i) {
      const int idx = i * 256 + t;           // 0..511
      const int r   = idx >> 2;              // 0..127
      const int k16 = idx & 3;               // 0..3
      const float* src = z + (long long)(mt * 128 + r) * KDIM + kt * 32 + k16 * 8;
      const float4 v0 = *(const float4*)src;
      const float4 v1 = *(const float4*)(src + 4);
      const float vv[8] = {v0.x, v0.y, v0.z, v0.w, v1.x, v1.y, v1.z, v1.w};
      ushort8 h, l;
#pragma unroll
      for (int j = 0; j < 8; ++j) {
        const unsigned short hs = f2bf(vv[j]);
        h[j] = hs; l[j] = f2bf(vv[j] - bf2f(hs));
      }
      const long long o = tb + (long long)(k16 * 128 + r) * 8;
      *(ushort8*)&Ah[o] = h;
      *(ushort8*)&Al[o] = l;
    }
  } else {
    // ---------------- W1 path ----------------
    const int nt = blockIdx.y - MT;
    const float* src = W1 + (long long)(kt * 32) * N1 + nt * 128;
#pragma unroll
    for (int i = 0; i < 4; ++i) {
      const int idx = i * 256 + t, r = idx >> 5, c4 = idx & 31;
      const float4 v = *(const float4*)(src + (long long)r * N1 + c4 * 4);
      tile[r][c4 * 4 + 0] = v.x; tile[r][c4 * 4 + 1] = v.y;
      tile[r][c4 * 4 + 2] = v.z; tile[r][c4 * 4 + 3] = v.w;
    }
    __syncthreads();
    const long long tb = (long long)(nt * KT + kt) * TILE_E;
#pragma unroll
    for (int i = 0; i < 2; ++i) {
      const int q = i * 256 + t, k16 = q >> 7, col = q & 127;
      ushort8 h, l;
#pragma unroll
      for (int j = 0; j < 8; ++j) {
        const float f = tile[k16 * 8 + j][col];
        const unsigned short hs = f2bf(f);
        h[j] = hs; l[j] = f2bf(f - bf2f(hs));
      }
      *(ushort8*)&Bh[tb + q * 8] = h;
      *(ushort8*)&Bl[tb + q * 8] = l;
    }
  }
}

// ----------------------- GEMM1: split-3 bf16 MFMA ---------------------------
// 128x256 tile, BK=32, 8 waves (2x4) of 64x64, 16x16x32 MFMA, 4x4 frags,
// single-buffer 48KB LDS, 2 blocks/CU, K-split-8 -> 512 blocks of 512 thr.
// LDS layout (shorts): Ah[0,4K) Al[4K,8K) Bh[8K,16K) Bl[16K,24K);
// B addressed as two adjacent 128-col split tiles (sub = col>>7).
__global__ __launch_bounds__(512, 4)
void gemm_sb(const unsigned short* __restrict__ Ah, const unsigned short* __restrict__ Al,
             const unsigned short* __restrict__ Bh, const unsigned short* __restrict__ Bl,
             const float* __restrict__ b1, float* __restrict__ e1p)
{
  __shared__ unsigned short lds[6 * 4096];   // 48 KB
  const int t = threadIdx.x, lane = t & 63, w = t >> 6;   // w: 0..7
  const int wr = w >> 2, wc = w & 3;                      // wave tile: 64x64
  const int bid = blockIdx.x;
  const int wg = (bid & 7) * 64 + (bid >> 3);    // XCD chunked swizzle, 512%8==0
  const int ks  = wg >> 6;                       // 0..7
  const int mt  = (wg >> 2) & 15;                // 0..15
  const int nt2 = wg & 3;                        // 0..3 (256-wide n-tile)
  const int s0 = ks * QS;
  const int nst = min(QS, KT - s0);              // 47 x7, 46 last

  const unsigned short* ga0  = Ah + (long long)(mt * KT + s0) * TILE_E;
  const unsigned short* ga1  = Al + (long long)(mt * KT + s0) * TILE_E;
  const unsigned short* gb0h = Bh + (long long)((2 * nt2)     * KT + s0) * TILE_E;
  const unsigned short* gb1h = Bh + (long long)((2 * nt2 + 1) * KT + s0) * TILE_E;
  const unsigned short* gb0l = Bl + (long long)((2 * nt2)     * KT + s0) * TILE_E;
  const unsigned short* gb1l = Bl + (long long)((2 * nt2 + 1) * KT + s0) * TILE_E;

  f32x4 acc[4][4] = {};
  const int fr = lane & 15, k16 = lane >> 4;

  // per-lane LDS read offsets (shorts), step-invariant
  int offA[4], offB[4];
#pragma unroll
  for (int mf = 0; mf < 4; ++mf)
    offA[mf] = k16 * 1024 + (wr * 64 + mf * 16 + fr) * 8;
#pragma unroll
  for (int nf = 0; nf < 4; ++nf) {
    const int col = wc * 64 + nf * 16 + fr;      // 0..255
    offB[nf] = 8192 + (col >> 7) * 4096 + k16 * 1024 + (col & 127) * 8;
  }

  for (int s = 0; s < nst; ++s) {
    // stage current K-step into the single buffer (6 x 8KB)
    const long long so = (long long)s * TILE_E + t * 8;
    gl_lds16(ga0  + so, &lds[            t * 8]);
    gl_lds16(ga1  + so, &lds[ 4096     + t * 8]);
    gl_lds16(gb0h + so, &lds[ 8192     + t * 8]);
    gl_lds16(gb1h + so, &lds[12288     + t * 8]);
    gl_lds16(gb0l + so, &lds[16384     + t * 8]);
    gl_lds16(gb1l + so, &lds[20480     + t * 8]);
    __syncthreads();                       // vmcnt(0) drain + barrier: tile ready

    bf16x8 a0[4], b0[4], x[4];
#pragma unroll
    for (int mf = 0; mf < 4; ++mf) a0[mf] = *(const bf16x8*)&lds[offA[mf]];
#pragma unroll
    for (int nf = 0; nf < 4; ++nf) b0[nf] = *(const bf16x8*)&lds[offB[nf]];
    __builtin_amdgcn_s_setprio(1);
    // pass 1: ah x bh
#pragma unroll
    for (int mf = 0; mf < 4; ++mf)
#pragma unroll
      for (int nf = 0; nf < 4; ++nf)
        acc[mf][nf] = __builtin_amdgcn_mfma_f32_16x16x32_bf16(a0[mf], b0[nf], acc[mf][nf], 0, 0, 0);
    // pass 2: ah x bl  (x <- Bl frags)
#pragma unroll
    for (int nf = 0; nf < 4; ++nf) x[nf] = *(const bf16x8*)&lds[offB[nf] + 8192];
#pragma unroll
    for (int mf = 0; mf < 4; ++mf)
#pragma unroll
      for (int nf = 0; nf < 4; ++nf)
        acc[mf][nf] = __builtin_amdgcn_mfma_f32_16x16x32_bf16(a0[mf], x[nf], acc[mf][nf], 0, 0, 0);
    // pass 3: al x bh  (x <- Al frags)
#pragma unroll
    for (int mf = 0; mf < 4; ++mf) x[mf] = *(const bf16x8*)&lds[offA[mf] + 4096];
#pragma unroll
    for (int mf = 0; mf < 4; ++mf)
#pragma unroll
      for (int nf = 0; nf < 4; ++nf)
        acc[mf][nf] = __builtin_amdgcn_mfma_f32_16x16x32_bf16(x[mf], b0[nf], acc[mf][nf], 0, 0, 0);
    __builtin_amdgcn_s_setprio(0);
    __syncthreads();                       // all reads done before next stage
  }

  // Epilogue: 16x16 C/D layout col=lane&15, row=(lane>>4)*4+reg (r3-verified)
  float* eo = e1p + (long long)ks * MROWS * N1;
#pragma unroll
  for (int mf = 0; mf < 4; ++mf) {
    const int r0 = mt * 128 + wr * 64 + mf * 16 + ((lane >> 4) << 2);
#pragma unroll
    for (int nf = 0; nf < 4; ++nf) {
      const int col = nt2 * 256 + wc * 64 + nf * 16 + (lane & 15);
      const float bias = (ks == 0) ? b1[col] : 0.0f;
#pragma unroll
      for (int r = 0; r < 4; ++r)
        eo[(long long)(r0 + r) * N1 + col] = acc[mf][nf][r] + bias;
    }
  }
}

// ------------------------ GEMM2 + distances + argmax ------------------------
// r7 head: cooperative LDS reduction of NKS=8 partials (compile-time
// unrolled, coalesced f32x4), GEMM2 from LDS broadcast, distances + argmax.
constexpr int RPB = 8;

__global__ __launch_bounds__(256, 2)
void head_kernel(const float* __restrict__ e1, const float* __restrict__ W2,
                 const float* __restrict__ b2, const float* __restrict__ cents,
                 float* __restrict__ eOut, float* __restrict__ sOut,
                 float* __restrict__ cOut)
{
  __shared__ float e_red[RPB][N1];        // 32 KB: reduced e1 rows
  __shared__ float cent_s[NCL * 65];      // 26 KB
  __shared__ float e_s[RPB][N2 + 4];
  const int t = threadIdx.x;
  const int r0 = blockIdx.x * RPB;
  constexpr long long PS = (long long)MROWS * N1;

  for (int i = t; i < NCL * N2; i += 256) {
    const int c = i >> 6, d = i & 63;
    cent_s[c * 65 + d] = cents[i];
  }

  // phase 1: reduce NKS partials into e_red (coalesced 1KB/wave loads)
#pragma unroll
  for (int v = 0; v < 8; ++v) {
    const int idx = v * 256 + t;          // 0..2047
    const int row = idx >> 8;             // 0..7
    const int c4  = idx & 255;            // f32x4 slot within row
    const float* src = e1 + (long long)(r0 + row) * N1 + c4 * 4;
    f32x4 x = *(const f32x4*)src;
#pragma unroll
    for (int p = 1; p < NKS; ++p) x += *(const f32x4*)(src + (long long)p * PS);
    *(f32x4*)&e_red[row][c4 * 4] = x;
  }
  __syncthreads();

  // phase 2: GEMM2 from LDS (wave-uniform broadcast reads, conflict-free)
  const int n = t & 63;
  const int rq = t >> 6;
  float acc0 = 0.f, acc1 = 0.f;
  for (int k = 0; k < N1; k += 4) {
    const f32x4 x0 = *(const f32x4*)&e_red[rq][k];
    const f32x4 x1 = *(const f32x4*)&e_red[rq + 4][k];
    const float w0 = W2[(k + 0) * N2 + n];
    const float w1 = W2[(k + 1) * N2 + n];
    const float w2 = W2[(k + 2) * N2 + n];
    const float w3 = W2[(k + 3) * N2 + n];
    acc0 = fmaf(x0[0], w0, acc0); acc0 = fmaf(x0[1], w1, acc0);
    acc0 = fmaf(x0[2], w2, acc0); acc0 = fmaf(x0[3], w3, acc0);
    acc1 = fmaf(x1[0], w0, acc1); acc1 = fmaf(x1[1], w1, acc1);
    acc1 = fmaf(x1[2], w2, acc1); acc1 = fmaf(x1[3], w3, acc1);
  }
  acc0 += b2[n]; acc1 += b2[n];
  eOut[(long long)(r0 + rq) * N2 + n]     = acc0;
  eOut[(long long)(r0 + rq + 4) * N2 + n] = acc1;
  e_s[rq][n]     = acc0;
  e_s[rq + 4][n] = acc1;
  __syncthreads();

  // phase 3: distances + row-normalize + argmax
  const int row = t >> 5;
  const int ci  = t & 31;
  float sum = 0.f, bestv = -1.f;
  int bestc = 0;
  float sv[4] = {0.f, 0.f, 0.f, 0.f};
#pragma unroll
  for (int j = 0; j < 4; ++j) {
    const int c = ci + 32 * j;
    if (c < NCL) {
      float d2 = 0.f;
#pragma unroll 8
      for (int d = 0; d < N2; ++d) {
        const float diff = e_s[row][d] - cent_s[c * 65 + d];
        d2 = fmaf(diff, diff, d2);
      }
      const float su = 1.0f / (1.0f + sqrtf(d2));
      sv[j] = su; sum += su;
      if (su > bestv) { bestv = su; bestc = c; }
    }
  }
#pragma unroll
  for (int off = 1; off < 32; off <<= 1) {
    sum += __shfl_xor(sum, off);
    const float ov = __shfl_xor(bestv, off);
    const int   oc = __shfl_xor(bestc, off);
    if (ov > bestv || (ov == bestv && oc < bestc)) { bestv = ov; bestc = oc; }
  }
  const float inv = 1.0f / sum;
#pragma unroll
  for (int j = 0; j < 4; ++j) {
    const int c = ci + 32 * j;
    if (c < NCL) sOut[(long long)(r0 + row) * NCL + c] = sv[j] * inv;
  }
  if (ci == 0) cOut[r0 + row] = (float)bestc;
}

// --------------------------------- launch -----------------------------------
extern "C" void kernel_launch(void* const* d_in, const int* in_sizes, int n_in,
                              void* d_out, int out_size, void* d_ws, size_t ws_size,
                              hipStream_t stream)
{
  const float* z     = (const float*)d_in[0];
  const float* W1    = (const float*)d_in[1];
  const float* b1    = (const float*)d_in[2];
  const float* W2    = (const float*)d_in[3];
  const float* b2    = (const float*)d_in[4];
  const float* cents = (const float*)d_in[5];
  float* out  = (float*)d_out;
  float* eOut = out;
  float* sOut = out + MROWS * N2;
  float* cOut = out + MROWS * N2 + MROWS * NCL;

  unsigned short* Ah = (unsigned short*)d_ws;
  unsigned short* Al = Ah + AE;
  unsigned short* Bh = Al + AE;
  unsigned short* Bl = Bh + BE;
  float* e1p = (float*)(Bl + BE);   // 8 partials = 64 MB (nks=8 path r6-validated)

  split_zw<<<dim3(KT, MT + NT), 256, 0, stream>>>(z, W1, Ah, Al, Bh, Bl);
  gemm_sb<<<512, 512, 0, stream>>>(Ah, Al, Bh, Bl, b1, e1p);
  head_kernel<<<MROWS / RPB, 256, 0, stream>>>(e1p, W2, b2, cents, eOut, sOut, cOut);
}

// Round 11
// 200.826 us; speedup vs baseline: 1.1476x; 1.0058x over previous
//
#include <hip/hip_runtime.h>
#include <hip/hip_bf16.h>
#include <math.h>

// ---------------------------------------------------------------------------
// ClusteringModule: e = (z@W1+b1)@W2+b2 ; s = rownorm(1/(1+||e-c||)) ; c=argmax
// Round 14: barrier-tax amortization. GEMM1 = 128x128 tile, BK=64 per
// barrier pair: single-buffered 64KB LDS (4 arrays x 16KB), 2 blocks/CU,
// 8 waves x (32x64) r3 fragment mapping, two BK=32 halves computed between
// one sync pair (compiler overlaps kk=1 ds_reads under kk=0 MFMAs).
// Per-CU-step matrix work doubles (7450 cyc) against one ~2500-cyc stall
// event -> predicted MfmaUtil 57 -> ~70%. Numerics identical to r3/r8
// (same k-tile order, same 3-pass order). K-split-4, head NKS=4 (r8 head),
// split_zw unchanged (r12).
// ---------------------------------------------------------------------------

typedef __bf16 bf16x8 __attribute__((ext_vector_type(8)));
typedef float  f32x4  __attribute__((ext_vector_type(4)));
typedef unsigned short ushort8 __attribute__((ext_vector_type(8)));

#define MROWS 2048
#define KDIM  12000
#define N1    1024
#define N2    64
#define NCL   100

constexpr int KT = 375;          // k-tiles of 32
constexpr int MT = 16;           // m-tiles of 128
constexpr int NT = 8;            // n-tiles of 128
constexpr int TILE_E = 4096;     // 128x32 bf16 elems per tile (8192 B)
constexpr long long AE = (long long)MT * KT * TILE_E;
constexpr long long BE = (long long)NT * KT * TILE_E;

__device__ __forceinline__ unsigned short f2bf(float f) {
  unsigned int u = __float_as_uint(f);
  return (unsigned short)((u + 0x7FFFu + ((u >> 16) & 1u)) >> 16);   // RNE
}
__device__ __forceinline__ float bf2f(unsigned short h) {
  return __uint_as_float(((unsigned int)h) << 16);
}

__device__ __forceinline__ void gl_lds16(const unsigned short* g, unsigned short* l) {
  __builtin_amdgcn_global_load_lds((const __attribute__((address_space(1))) void*)g,
                                   (__attribute__((address_space(3))) void*)l, 16, 0, 0);
}

// ------------- fused pre-split: z -> Ah/Al  and  W1 -> Bh/Bl ---------------
__global__ __launch_bounds__(256)
void split_zw(const float* __restrict__ z, const float* __restrict__ W1,
              unsigned short* __restrict__ Ah, unsigned short* __restrict__ Al,
              unsigned short* __restrict__ Bh, unsigned short* __restrict__ Bl)
{
  __shared__ float tile[32][129];          // W1-path only (16.5 KB)
  const int t  = threadIdx.x;
  const int kt = blockIdx.x;

  if (blockIdx.y < MT) {
    // ---------------- z path ----------------
    const int mt = blockIdx.y;
    const long long tb = (long long)(mt * KT + kt) * TILE_E;
#pragma unroll
    for (int i = 0; i < 2; ++i) {
      const int idx = i * 256 + t;           // 0..511
      const int r   = idx >> 2;              // 0..127
      const int k16 = idx & 3;               // 0..3
      const float* src = z + (long long)(mt * 128 + r) * KDIM + kt * 32 + k16 * 8;
      const float4 v0 = *(const float4*)src;
      const float4 v1 = *(const float4*)(src + 4);
      const float vv[8] = {v0.x, v0.y, v0.z, v0.w, v1.x, v1.y, v1.z, v1.w};
      ushort8 h, l;
#pragma unroll
      for (int j = 0; j < 8; ++j) {
        const unsigned short hs = f2bf(vv[j]);
        h[j] = hs; l[j] = f2bf(vv[j] - bf2f(hs));
      }
      const long long o = tb + (long long)(k16 * 128 + r) * 8;
      *(ushort8*)&Ah[o] = h;
      *(ushort8*)&Al[o] = l;
    }
  } else {
    // ---------------- W1 path ----------------
    const int nt = blockIdx.y - MT;
    const float* src = W1 + (long long)(kt * 32) * N1 + nt * 128;
#pragma unroll
    for (int i = 0; i < 4; ++i) {
      const int idx = i * 256 + t, r = idx >> 5, c4 = idx & 31;
      const float4 v = *(const float4*)(src + (long long)r * N1 + c4 * 4);
      tile[r][c4 * 4 + 0] = v.x; tile[r][c4 * 4 + 1] = v.y;
      tile[r][c4 * 4 + 2] = v.z; tile[r][c4 * 4 + 3] = v.w;
    }
    __syncthreads();
    const long long tb = (long long)(nt * KT + kt) * TILE_E;
#pragma unroll
    for (int i = 0; i < 2; ++i) {
      const int q = i * 256 + t, k16 = q >> 7, col = q & 127;
      ushort8 h, l;
#pragma unroll
      for (int j = 0; j < 8; ++j) {
        const float f = tile[k16 * 8 + j][col];
        const unsigned short hs = f2bf(f);
        h[j] = hs; l[j] = f2bf(f - bf2f(hs));
      }
      *(ushort8*)&Bh[tb + q * 8] = h;
      *(ushort8*)&Bl[tb + q * 8] = l;
    }
  }
}

// ----------------------- GEMM1: split-3 bf16 MFMA, BK=64 --------------------
// 128x128 tile, 8 waves x (32x64), K-split-4 -> 512 blocks of 512 thr.
// Single-buffered 64KB LDS holding TWO consecutive BK=32 tiles per array;
// one barrier pair per BK=64. 2 blocks/CU = 4 waves/SIMD.
__global__ __launch_bounds__(512, 4)
void gemm_bk64(const unsigned short* __restrict__ Ah, const unsigned short* __restrict__ Al,
               const unsigned short* __restrict__ Bh, const unsigned short* __restrict__ Bl,
               const float* __restrict__ b1, float* __restrict__ e1p)
{
  __shared__ unsigned short lds[4][2 * TILE_E];   // 64 KB single buffer
  const int t = threadIdx.x, lane = t & 63, w = t >> 6;   // w: 0..7
  const int wr = w >> 1, wc = w & 1;                      // wave tile: 32x64
  const int bid = blockIdx.x;
  const int wg = ((bid & 7) << 6) | (bid >> 3);  // XCD chunked swizzle, 512%8==0
  const int ks = wg >> 7;
  const int mt = (wg >> 3) & 15;
  const int nt = wg & 7;
  const int s0 = ks * 94;
  const int nst32 = (ks == 3) ? 93 : 94;         // BK=32 tiles in this slice
  const int nfull = nst32 >> 1;                  // BK=64 steps: 47,47,47,46
  const int tail  = nst32 & 1;                   // 0,0,0,1

  const unsigned short* ga0 = Ah + (long long)(mt * KT + s0) * TILE_E;
  const unsigned short* ga1 = Al + (long long)(mt * KT + s0) * TILE_E;
  const unsigned short* ga2 = Bh + (long long)(nt * KT + s0) * TILE_E;
  const unsigned short* ga3 = Bl + (long long)(nt * KT + s0) * TILE_E;

  f32x4 acc[2][4] = {};
  const int fr = lane & 15, k16 = lane >> 4;

  // per-lane LDS offsets within one BK=32 tile (shorts), step-invariant
  int offA[2], offB[4];
#pragma unroll
  for (int mf = 0; mf < 2; ++mf)
    offA[mf] = k16 * 1024 + (wr * 32 + mf * 16 + fr) * 8;
#pragma unroll
  for (int nf = 0; nf < 4; ++nf)
    offB[nf] = k16 * 1024 + (wc * 64 + nf * 16 + fr) * 8;

  auto compute_half = [&](int kb) {   // kb = 0 or TILE_E (which BK=32 half)
    bf16x8 ah[2], al[2], bh[4], bl[4];
#pragma unroll
    for (int mf = 0; mf < 2; ++mf) {
      ah[mf] = *(const bf16x8*)&lds[0][kb + offA[mf]];
      al[mf] = *(const bf16x8*)&lds[1][kb + offA[mf]];
    }
#pragma unroll
    for (int nf = 0; nf < 4; ++nf) {
      bh[nf] = *(const bf16x8*)&lds[2][kb + offB[nf]];
      bl[nf] = *(const bf16x8*)&lds[3][kb + offB[nf]];
    }
    __builtin_amdgcn_s_setprio(1);
#pragma unroll
    for (int mf = 0; mf < 2; ++mf)
#pragma unroll
      for (int nf = 0; nf < 4; ++nf)
        acc[mf][nf] = __builtin_amdgcn_mfma_f32_16x16x32_bf16(ah[mf], bh[nf], acc[mf][nf], 0, 0, 0);
#pragma unroll
    for (int mf = 0; mf < 2; ++mf)
#pragma unroll
      for (int nf = 0; nf < 4; ++nf)
        acc[mf][nf] = __builtin_amdgcn_mfma_f32_16x16x32_bf16(ah[mf], bl[nf], acc[mf][nf], 0, 0, 0);
#pragma unroll
    for (int mf = 0; mf < 2; ++mf)
#pragma unroll
      for (int nf = 0; nf < 4; ++nf)
        acc[mf][nf] = __builtin_amdgcn_mfma_f32_16x16x32_bf16(al[mf], bh[nf], acc[mf][nf], 0, 0, 0);
    __builtin_amdgcn_s_setprio(0);
  };

  for (int s = 0; s < nfull; ++s) {
    // stage TWO consecutive BK=32 tiles per array (8 x 8KB = 64KB)
    const long long so = (long long)(2 * s) * TILE_E + t * 8;
    gl_lds16(ga0 + so,          &lds[0][t * 8]);
    gl_lds16(ga0 + so + TILE_E, &lds[0][TILE_E + t * 8]);
    gl_lds16(ga1 + so,          &lds[1][t * 8]);
    gl_lds16(ga1 + so + TILE_E, &lds[1][TILE_E + t * 8]);
    gl_lds16(ga2 + so,          &lds[2][t * 8]);
    gl_lds16(ga2 + so + TILE_E, &lds[2][TILE_E + t * 8]);
    gl_lds16(ga3 + so,          &lds[3][t * 8]);
    gl_lds16(ga3 + so + TILE_E, &lds[3][TILE_E + t * 8]);
    __syncthreads();                       // drain + barrier: both halves ready
    compute_half(0);                       // kk=0 (tile order matches r3)
    compute_half(TILE_E);                  // kk=1
    __syncthreads();                       // all reads done before next stage
  }
  if (tail) {                              // slice 3: one leftover BK=32 tile
    const long long so = (long long)(2 * nfull) * TILE_E + t * 8;
    gl_lds16(ga0 + so, &lds[0][t * 8]);
    gl_lds16(ga1 + so, &lds[1][t * 8]);
    gl_lds16(ga2 + so, &lds[2][t * 8]);
    gl_lds16(ga3 + so, &lds[3][t * 8]);
    __syncthreads();
    compute_half(0);
  }

  // Epilogue: 16x16 C/D layout col=lane&15, row=(lane>>4)*4+reg (r3-verified)
  float* eo = e1p + (long long)ks * MROWS * N1;
#pragma unroll
  for (int mf = 0; mf < 2; ++mf) {
    const int r0 = mt * 128 + wr * 32 + mf * 16 + ((lane >> 4) << 2);
#pragma unroll
    for (int nf = 0; nf < 4; ++nf) {
      const int col = nt * 128 + wc * 64 + nf * 16 + (lane & 15);
      const float bias = (ks == 0) ? b1[col] : 0.0f;
#pragma unroll
      for (int r = 0; r < 4; ++r)
        eo[(long long)(r0 + r) * N1 + col] = acc[mf][nf][r] + bias;
    }
  }
}

// ------------------------ GEMM2 + distances + argmax ------------------------
// r7/r8 head: cooperative LDS reduction of NKS=4 partials, GEMM2 from LDS
// broadcast, distances + argmax.
constexpr int RPB = 8;
constexpr int NKS = 4;

__global__ __launch_bounds__(256, 2)
void head_kernel(const float* __restrict__ e1, const float* __restrict__ W2,
                 const float* __restrict__ b2, const float* __restrict__ cents,
                 float* __restrict__ eOut, float* __restrict__ sOut,
                 float* __restrict__ cOut)
{
  __shared__ float e_red[RPB][N1];        // 32 KB: reduced e1 rows
  __shared__ float cent_s[NCL * 65];      // 26 KB
  __shared__ float e_s[RPB][N2 + 4];
  const int t = threadIdx.x;
  const int r0 = blockIdx.x * RPB;
  constexpr long long PS = (long long)MROWS * N1;

  for (int i = t; i < NCL * N2; i += 256) {
    const int c = i >> 6, d = i & 63;
    cent_s[c * 65 + d] = cents[i];
  }

  // phase 1: reduce NKS partials into e_red (coalesced 1KB/wave loads)
#pragma unroll
  for (int v = 0; v < 8; ++v) {
    const int idx = v * 256 + t;          // 0..2047
    const int row = idx >> 8;             // 0..7
    const int c4  = idx & 255;            // f32x4 slot within row
    const float* src = e1 + (long long)(r0 + row) * N1 + c4 * 4;
    f32x4 x = *(const f32x4*)src;
#pragma unroll
    for (int p = 1; p < NKS; ++p) x += *(const f32x4*)(src + (long long)p * PS);
    *(f32x4*)&e_red[row][c4 * 4] = x;
  }
  __syncthreads();

  // phase 2: GEMM2 from LDS (wave-uniform broadcast reads, conflict-free)
  const int n = t & 63;
  const int rq = t >> 6;
  float acc0 = 0.f, acc1 = 0.f;
  for (int k = 0; k < N1; k += 4) {
    const f32x4 x0 = *(const f32x4*)&e_red[rq][k];
    const f32x4 x1 = *(const f32x4*)&e_red[rq + 4][k];
    const float w0 = W2[(k + 0) * N2 + n];
    const float w1 = W2[(k + 1) * N2 + n];
    const float w2 = W2[(k + 2) * N2 + n];
    const float w3 = W2[(k + 3) * N2 + n];
    acc0 = fmaf(x0[0], w0, acc0); acc0 = fmaf(x0[1], w1, acc0);
    acc0 = fmaf(x0[2], w2, acc0); acc0 = fmaf(x0[3], w3, acc0);
    acc1 = fmaf(x1[0], w0, acc1); acc1 = fmaf(x1[1], w1, acc1);
    acc1 = fmaf(x1[2], w2, acc1); acc1 = fmaf(x1[3], w3, acc1);
  }
  acc0 += b2[n]; acc1 += b2[n];
  eOut[(long long)(r0 + rq) * N2 + n]     = acc0;
  eOut[(long long)(r0 + rq + 4) * N2 + n] = acc1;
  e_s[rq][n]     = acc0;
  e_s[rq + 4][n] = acc1;
  __syncthreads();

  // phase 3: distances + row-normalize + argmax
  const int row = t >> 5;
  const int ci  = t & 31;
  float sum = 0.f, bestv = -1.f;
  int bestc = 0;
  float sv[4] = {0.f, 0.f, 0.f, 0.f};
#pragma unroll
  for (int j = 0; j < 4; ++j) {
    const int c = ci + 32 * j;
    if (c < NCL) {
      float d2 = 0.f;
#pragma unroll 8
      for (int d = 0; d < N2; ++d) {
        const float diff = e_s[row][d] - cent_s[c * 65 + d];
        d2 = fmaf(diff, diff, d2);
      }
      const float su = 1.0f / (1.0f + sqrtf(d2));
      sv[j] = su; sum += su;
      if (su > bestv) { bestv = su; bestc = c; }
    }
  }
#pragma unroll
  for (int off = 1; off < 32; off <<= 1) {
    sum += __shfl_xor(sum, off);
    const float ov = __shfl_xor(bestv, off);
    const int   oc = __shfl_xor(bestc, off);
    if (ov > bestv || (ov == bestv && oc < bestc)) { bestv = ov; bestc = oc; }
  }
  const float inv = 1.0f / sum;
#pragma unroll
  for (int j = 0; j < 4; ++j) {
    const int c = ci + 32 * j;
    if (c < NCL) sOut[(long long)(r0 + row) * NCL + c] = sv[j] * inv;
  }
  if (ci == 0) cOut[r0 + row] = (float)bestc;
}

// --------------------------------- launch -----------------------------------
extern "C" void kernel_launch(void* const* d_in, const int* in_sizes, int n_in,
                              void* d_out, int out_size, void* d_ws, size_t ws_size,
                              hipStream_t stream)
{
  const float* z     = (const float*)d_in[0];
  const float* W1    = (const float*)d_in[1];
  const float* b1    = (const float*)d_in[2];
  const float* W2    = (const float*)d_in[3];
  const float* b2    = (const float*)d_in[4];
  const float* cents = (const float*)d_in[5];
  float* out  = (float*)d_out;
  float* eOut = out;
  float* sOut = out + MROWS * N2;
  float* cOut = out + MROWS * N2 + MROWS * NCL;

  unsigned short* Ah = (unsigned short*)d_ws;
  unsigned short* Al = Ah + AE;
  unsigned short* Bh = Al + AE;
  unsigned short* Bl = Bh + BE;
  float* e1p = (float*)(Bl + BE);

  split_zw<<<dim3(KT, MT + NT), 256, 0, stream>>>(z, W1, Ah, Al, Bh, Bl);
  gemm_bk64<<<512, 512, 0, stream>>>(Ah, Al, Bh, Bl, b1, e1p);
  head_kernel<<<MROWS / RPB, 256, 0, stream>>>(e1p, W2, b2, cents, eOut, sOut, cOut);
}